// Round 1
// baseline (79.512 us; speedup 1.0000x reference)
//
#include <hip/hip_runtime.h>
#include <hip/hip_bf16.h>
#include <float.h>

typedef __attribute__((ext_vector_type(8))) short short8;
typedef __attribute__((ext_vector_type(4))) float f32x4;
typedef unsigned short ushort_t;

#define N_E   1024
#define E_DIM 256
#define N_TOKS 65536

// round-to-nearest-even fp32 -> bf16 (bit trick, same as v_cvt)
__device__ inline ushort_t f2bf(float f) {
  unsigned int u = __float_as_uint(f);
  unsigned int r = u + 0x7FFFu + ((u >> 16) & 1u);
  return (ushort_t)(r >> 16);
}

// ---------------------------------------------------------------------------
// Prep: emb fp32 -> bf16 in MFMA-B-fragment order + enorm = sum(e^2)
// Layout (bytes): embT[tile=code/16][ko=k/8][c16=code%16][j=k%8] *2B
//   byte = tile*8192 + ko*256 + c16*16 + j*2   (exactly the LDS tile image)
// ---------------------------------------------------------------------------
__global__ __launch_bounds__(256) void vq_prep(const float* __restrict__ emb,
                                               ushort_t* __restrict__ embT,
                                               float* __restrict__ enorm) {
  const int code = blockIdx.x;     // 0..1023
  const int t    = threadIdx.x;    // 0..255 = k
  float v = emb[(size_t)code * E_DIM + t];
  embT[(size_t)(code >> 4) * 4096 + (t >> 3) * 128 + (code & 15) * 8 + (t & 7)] = f2bf(v);
  float sq = v * v;
  #pragma unroll
  for (int m = 1; m < 64; m <<= 1) sq += __shfl_xor(sq, m);
  __shared__ float ws3[4];
  if ((t & 63) == 0) ws3[t >> 6] = sq;
  __syncthreads();
  if (t == 0) enorm[code] = ws3[0] + ws3[1] + ws3[2] + ws3[3];
}

// ---------------------------------------------------------------------------
// Main: per block = 128 tokens; 4 waves * 32 tokens (2 halves of 16).
// z in registers as bf16 A-frags; emb tiles (16 codes x 256 K) double-buffered
// in LDS via global_load_lds; running per-lane (best_score,best_idx);
// epilogue: gather emb rows -> out, loss_t = znorm_t + s_best_t.
// ---------------------------------------------------------------------------
__global__ __launch_bounds__(256, 2) void vq_main(
    const float* __restrict__ z, const float* __restrict__ emb,
    const ushort_t* __restrict__ embT, const float* __restrict__ enorm,
    float* __restrict__ out, float* __restrict__ partials) {
  __shared__ ushort_t ldsB[2][4096];   // 2 x 8 KB
  __shared__ float znorm_lds[128];
  __shared__ float s_lds[128];
  __shared__ int   idx_lds[128];
  __shared__ float wsum[4];

  const int tid  = threadIdx.x;
  const int lane = tid & 63;
  const int wv   = tid >> 6;
  const int blk  = blockIdx.x;
  const int lrow = lane & 15;   // A: token row within 16; B/D: code col
  const int lk   = lane >> 4;   // 0..3 k-group / D row-group

  // ---- A fragments (z -> bf16) + fp32 znorm --------------------------------
  short8 afr[2][8];
  #pragma unroll
  for (int h = 0; h < 2; ++h) {
    const float* zp = z + (size_t)(blk * 128 + wv * 32 + h * 16 + lrow) * E_DIM + lk * 8;
    float zn = 0.f;
    #pragma unroll
    for (int kk = 0; kk < 8; ++kk) {
      float4 v0 = *(const float4*)(zp + kk * 32);
      float4 v1 = *(const float4*)(zp + kk * 32 + 4);
      zn += v0.x * v0.x + v0.y * v0.y + v0.z * v0.z + v0.w * v0.w;
      zn += v1.x * v1.x + v1.y * v1.y + v1.z * v1.z + v1.w * v1.w;
      short8 a;
      a[0] = (short)f2bf(v0.x); a[1] = (short)f2bf(v0.y);
      a[2] = (short)f2bf(v0.z); a[3] = (short)f2bf(v0.w);
      a[4] = (short)f2bf(v1.x); a[5] = (short)f2bf(v1.y);
      a[6] = (short)f2bf(v1.z); a[7] = (short)f2bf(v1.w);
      afr[h][kk] = a;
    }
    zn += __shfl_xor(zn, 16);
    zn += __shfl_xor(zn, 32);
    if (lane < 16) znorm_lds[wv * 32 + h * 16 + lane] = zn;
  }

  // ---- staging macro: tile = 16 codes x 256 k bf16 = 8 KB, linear copy -----
  const char* gbase = (const char*)embT;
#define STAGE(BUF, TILE) do {                                                  \
    const char* g = gbase + (size_t)(TILE) * 8192 + wv * 2048 + lane * 16;     \
    char* lp = ((char*)&ldsB[(BUF)][0]) + wv * 2048;                           \
    __builtin_amdgcn_global_load_lds(                                          \
        (const __attribute__((address_space(1))) void*)g,                      \
        (__attribute__((address_space(3))) void*)lp, 16, 0, 0);                \
    __builtin_amdgcn_global_load_lds(                                          \
        (const __attribute__((address_space(1))) void*)(g + 1024),             \
        (__attribute__((address_space(3))) void*)(lp + 1024), 16, 0, 0);       \
  } while (0)

  STAGE(0, 0);
  __syncthreads();

  float bs[2][4];
  int   bi[2][4];
  #pragma unroll
  for (int r = 0; r < 4; ++r) {
    bs[0][r] = FLT_MAX; bs[1][r] = FLT_MAX; bi[0][r] = 0; bi[1][r] = 0;
  }

  int buf = 0;
  for (int tile = 0; tile < 64; ++tile) {
    if (tile < 63) STAGE(buf ^ 1, tile + 1);          // prefetch next
    const float en = enorm[tile * 16 + lrow];
    f32x4 acc0 = {0.f, 0.f, 0.f, 0.f};
    f32x4 acc1 = {0.f, 0.f, 0.f, 0.f};
    const char* lb = (const char*)&ldsB[buf][0] + lk * 256 + lrow * 16;
    #pragma unroll
    for (int kk = 0; kk < 8; ++kk) {
      short8 bfr = *(const short8*)(lb + kk * 1024);
      acc0 = __builtin_amdgcn_mfma_f32_16x16x32_bf16(afr[0][kk], bfr, acc0, 0, 0, 0);
      acc1 = __builtin_amdgcn_mfma_f32_16x16x32_bf16(afr[1][kk], bfr, acc1, 0, 0, 0);
    }
    const int codeCol = tile * 16 + lrow;
    #pragma unroll
    for (int r = 0; r < 4; ++r) {
      float s0 = fmaf(-2.f, acc0[r], en);
      if (s0 < bs[0][r]) { bs[0][r] = s0; bi[0][r] = codeCol; }
      float s1 = fmaf(-2.f, acc1[r], en);
      if (s1 < bs[1][r]) { bs[1][r] = s1; bi[1][r] = codeCol; }
    }
    __syncthreads();   // staged next tile complete; all reads of buf done
    buf ^= 1;
  }
#undef STAGE

  // ---- cross-lane argmin reduce over the 16 code columns -------------------
  #pragma unroll
  for (int m = 1; m < 16; m <<= 1) {
    #pragma unroll
    for (int h = 0; h < 2; ++h) {
      #pragma unroll
      for (int r = 0; r < 4; ++r) {
        float s2 = __shfl_xor(bs[h][r], m);
        int   i2 = __shfl_xor(bi[h][r], m);
        if (s2 < bs[h][r] || (s2 == bs[h][r] && i2 < bi[h][r])) {
          bs[h][r] = s2; bi[h][r] = i2;
        }
      }
    }
  }
  if (lrow == 0) {
    #pragma unroll
    for (int h = 0; h < 2; ++h) {
      #pragma unroll
      for (int r = 0; r < 4; ++r) {
        const int t = wv * 32 + h * 16 + lk * 4 + r;   // D row = lk*4 + r
        s_lds[t]   = bs[h][r];
        idx_lds[t] = bi[h][r];
      }
    }
  }
  __syncthreads();

  // ---- epilogue: gather z_q rows (coalesced) -------------------------------
  const size_t outBase = (size_t)blk * 128;
  #pragma unroll 4
  for (int t = 0; t < 128; ++t) {
    const int ci = idx_lds[t];
    out[(outBase + t) * E_DIM + tid] = emb[(size_t)ci * E_DIM + tid];
  }

  // ---- loss: sum_t (znorm_t + s_best_t) ------------------------------------
  float lt = 0.f;
  if (tid < 128) lt = znorm_lds[tid] + s_lds[tid];
  #pragma unroll
  for (int m = 1; m < 64; m <<= 1) lt += __shfl_xor(lt, m);
  if (lane == 0) wsum[wv] = lt;
  __syncthreads();
  if (tid == 0) partials[blk] = wsum[0] + wsum[1] + wsum[2] + wsum[3];
}

// ---------------------------------------------------------------------------
// Final deterministic loss reduction: 512 partials -> scalar
// ---------------------------------------------------------------------------
__global__ __launch_bounds__(256) void vq_loss(const float* __restrict__ partials,
                                               float* __restrict__ lossOut) {
  const int tid = threadIdx.x;
  float v = partials[tid] + partials[tid + 256];
  #pragma unroll
  for (int m = 1; m < 64; m <<= 1) v += __shfl_xor(v, m);
  __shared__ float ws2[4];
  if ((tid & 63) == 0) ws2[tid >> 6] = v;
  __syncthreads();
  if (tid == 0)
    lossOut[0] = (ws2[0] + ws2[1] + ws2[2] + ws2[3]) * (1.25f / 16777216.f);
}

extern "C" void kernel_launch(void* const* d_in, const int* in_sizes, int n_in,
                              void* d_out, int out_size, void* d_ws, size_t ws_size,
                              hipStream_t stream) {
  const float* z   = (const float*)d_in[0];   // 65536 x 256 fp32
  const float* emb = (const float*)d_in[1];   // 1024 x 256 fp32
  float* out = (float*)d_out;                 // 16777216 + 1 fp32

  char* ws = (char*)d_ws;
  ushort_t* embT   = (ushort_t*)ws;                  // 512 KB
  float*    enorm  = (float*)(ws + 524288);          // 4 KB
  float*    parts  = (float*)(ws + 524288 + 4096);   // 2 KB

  vq_prep<<<N_E, 256, 0, stream>>>(emb, embT, enorm);
  vq_main<<<N_TOKS / 128, 256, 0, stream>>>(z, emb, embT, enorm, out, parts);
  vq_loss<<<1, 256, 0, stream>>>(parts, out + (size_t)N_TOKS * E_DIM);
}

// Round 2
// 69.665 us; speedup vs baseline: 1.1413x; 1.1413x over previous
//
#include <hip/hip_runtime.h>
#include <hip/hip_bf16.h>
#include <float.h>

typedef __attribute__((ext_vector_type(8))) short short8;
typedef __attribute__((ext_vector_type(4))) float f32x4;
typedef unsigned short ushort_t;

#define N_E   1024
#define E_DIM 256
#define N_TOKS 65536

// round-to-nearest-even fp32 -> bf16
__device__ inline ushort_t f2bf(float f) {
  unsigned int u = __float_as_uint(f);
  unsigned int r = u + 0x7FFFu + ((u >> 16) & 1u);
  return (ushort_t)(r >> 16);
}

// ---------------------------------------------------------------------------
// Prep: emb fp32 -> bf16 in MFMA-B-fragment order + enorm = sum(e^2)
// byte = (code/16)*8192 + (k/8)*256 + (code%16)*16 + (k%8)*2
// ---------------------------------------------------------------------------
__global__ __launch_bounds__(256) void vq_prep(const float* __restrict__ emb,
                                               ushort_t* __restrict__ embT,
                                               float* __restrict__ enorm) {
  const int code = blockIdx.x;     // 0..1023
  const int t    = threadIdx.x;    // 0..255 = k
  float v = emb[(size_t)code * E_DIM + t];
  embT[(size_t)(code >> 4) * 4096 + (t >> 3) * 128 + (code & 15) * 8 + (t & 7)] = f2bf(v);
  float sq = v * v;
  #pragma unroll
  for (int m = 1; m < 64; m <<= 1) sq += __shfl_xor(sq, m);
  __shared__ float ws3[4];
  if ((t & 63) == 0) ws3[t >> 6] = sq;
  __syncthreads();
  if (t == 0) enorm[code] = ws3[0] + ws3[1] + ws3[2] + ws3[3];
}

// ---------------------------------------------------------------------------
// Main: block = 128 tokens, 4 waves. z as bf16 A-frags in registers.
// 32 tiles of 32 codes (16 KB), TRIPLE-buffered LDS, counted vmcnt(4) +
// raw s_barrier so prefetch DMA stays in flight across barriers (T3+T4).
// ---------------------------------------------------------------------------
__global__ __launch_bounds__(256, 2) void vq_main(
    const float* __restrict__ z, const float* __restrict__ emb,
    const ushort_t* __restrict__ embT, const float* __restrict__ enorm,
    float* __restrict__ out, float* __restrict__ partials) {
  __shared__ ushort_t ldsB[3][8192];     // 3 x 16 KB
  __shared__ float enorm_lds[N_E];       // 4 KB
  __shared__ float znorm_lds[128];
  __shared__ float s_lds[128];
  __shared__ int   idx_lds[128];
  __shared__ float wsum[4];

  const int tid  = threadIdx.x;
  const int lane = tid & 63;
  const int wv   = tid >> 6;
  const int blk  = blockIdx.x;
  const int lrow = lane & 15;   // A: token row; B/D: code col
  const int lk   = lane >> 4;   // k-group / D row-group

  const char* gbase = (const char*)embT;
  // tile = 32 codes x 256 k = 16 KB; each wave stages its 4 KB quarter
#define STAGE(BUF, TILE) do {                                                  \
    const char* g = gbase + (size_t)(TILE) * 16384 + wv * 4096 + lane * 16;    \
    char* lp = ((char*)&ldsB[(BUF)][0]) + wv * 4096;                           \
    _Pragma("unroll")                                                          \
    for (int i_ = 0; i_ < 4; ++i_)                                             \
      __builtin_amdgcn_global_load_lds(                                        \
          (const __attribute__((address_space(1))) void*)(g + i_ * 1024),      \
          (__attribute__((address_space(3))) void*)(lp + i_ * 1024), 16, 0, 0);\
  } while (0)

  // prefetch tiles 0,1 early — latency hides under the z load phase below
  STAGE(0, 0);
  STAGE(1, 1);

  // ---- A fragments (z -> bf16) + fp32 znorm --------------------------------
  short8 afr[2][8];
  #pragma unroll
  for (int h = 0; h < 2; ++h) {
    const float* zp = z + (size_t)(blk * 128 + wv * 32 + h * 16 + lrow) * E_DIM + lk * 8;
    float zn = 0.f;
    #pragma unroll
    for (int kk = 0; kk < 8; ++kk) {
      float4 v0 = *(const float4*)(zp + kk * 32);
      float4 v1 = *(const float4*)(zp + kk * 32 + 4);
      zn += v0.x * v0.x + v0.y * v0.y + v0.z * v0.z + v0.w * v0.w;
      zn += v1.x * v1.x + v1.y * v1.y + v1.z * v1.z + v1.w * v1.w;
      short8 a;
      a[0] = (short)f2bf(v0.x); a[1] = (short)f2bf(v0.y);
      a[2] = (short)f2bf(v0.z); a[3] = (short)f2bf(v0.w);
      a[4] = (short)f2bf(v1.x); a[5] = (short)f2bf(v1.y);
      a[6] = (short)f2bf(v1.z); a[7] = (short)f2bf(v1.w);
      afr[h][kk] = a;
    }
    zn += __shfl_xor(zn, 16);
    zn += __shfl_xor(zn, 32);
    if (lane < 16) znorm_lds[wv * 32 + h * 16 + lane] = zn;
  }

  // enorm -> LDS (once)
  ((float4*)enorm_lds)[tid] = ((const float4*)enorm)[tid];

  __syncthreads();   // full barrier: enorm/znorm LDS writes + prologue DMA

  float bs[2][4];
  int   bi[2][4];
  #pragma unroll
  for (int r = 0; r < 4; ++r) {
    bs[0][r] = FLT_MAX; bs[1][r] = FLT_MAX; bi[0][r] = 0; bi[1][r] = 0;
  }

  int cb = 0;                       // compute-buffer index
  for (int t = 0; t < 32; ++t) {
    // tile t's 4 DMA loads are the oldest outstanding; keep t+1's in flight
    if (t < 31) asm volatile("s_waitcnt vmcnt(4)" ::: "memory");
    else        asm volatile("s_waitcnt vmcnt(0)" ::: "memory");
    __builtin_amdgcn_s_barrier();
    if (t + 2 < 32) {
      int st = cb + 2; if (st >= 3) st -= 3;
      STAGE(st, t + 2);
    }
    const char* tb = (const char*)&ldsB[cb][0] + lk * 256 + lrow * 16;
    #pragma unroll
    for (int c = 0; c < 2; ++c) {
      f32x4 acc0 = {0.f, 0.f, 0.f, 0.f};
      f32x4 acc1 = {0.f, 0.f, 0.f, 0.f};
      #pragma unroll
      for (int kk = 0; kk < 8; ++kk) {
        short8 bfr = *(const short8*)(tb + c * 8192 + kk * 1024);
        acc0 = __builtin_amdgcn_mfma_f32_16x16x32_bf16(afr[0][kk], bfr, acc0, 0, 0, 0);
        acc1 = __builtin_amdgcn_mfma_f32_16x16x32_bf16(afr[1][kk], bfr, acc1, 0, 0, 0);
      }
      const int code = t * 32 + c * 16 + lrow;
      const float en = enorm_lds[code];
      #pragma unroll
      for (int r = 0; r < 4; ++r) {
        float s0 = fmaf(-2.f, acc0[r], en);
        if (s0 < bs[0][r]) { bs[0][r] = s0; bi[0][r] = code; }
        float s1 = fmaf(-2.f, acc1[r], en);
        if (s1 < bs[1][r]) { bs[1][r] = s1; bi[1][r] = code; }
      }
    }
    cb = cb + 1; if (cb >= 3) cb = 0;
  }
#undef STAGE

  // ---- cross-lane argmin reduce over the 16 code columns -------------------
  #pragma unroll
  for (int m = 1; m < 16; m <<= 1) {
    #pragma unroll
    for (int h = 0; h < 2; ++h) {
      #pragma unroll
      for (int r = 0; r < 4; ++r) {
        float s2 = __shfl_xor(bs[h][r], m);
        int   i2 = __shfl_xor(bi[h][r], m);
        if (s2 < bs[h][r] || (s2 == bs[h][r] && i2 < bi[h][r])) {
          bs[h][r] = s2; bi[h][r] = i2;
        }
      }
    }
  }
  if (lrow == 0) {
    #pragma unroll
    for (int h = 0; h < 2; ++h) {
      #pragma unroll
      for (int r = 0; r < 4; ++r) {
        const int t = wv * 32 + h * 16 + lk * 4 + r;   // D row = lk*4 + r
        s_lds[t]   = bs[h][r];
        idx_lds[t] = bi[h][r];
      }
    }
  }
  __syncthreads();

  // ---- epilogue: gather z_q rows, one wave owns 32 tokens, float4/lane -----
  const float4* emb4 = (const float4*)emb;
  float4*       out4 = (float4*)out;
  const size_t outBase = (size_t)blk * 128;
  #pragma unroll 4
  for (int t2 = 0; t2 < 32; ++t2) {
    const int token = wv * 32 + t2;
    const int ci = idx_lds[token];
    out4[(outBase + token) * 64 + lane] = emb4[(size_t)ci * 64 + lane];
  }

  // ---- loss: sum_t (znorm_t + s_best_t) ------------------------------------
  float lt = 0.f;
  if (tid < 128) lt = znorm_lds[tid] + s_lds[tid];
  #pragma unroll
  for (int m = 1; m < 64; m <<= 1) lt += __shfl_xor(lt, m);
  if (lane == 0) wsum[wv] = lt;
  __syncthreads();
  if (tid == 0) partials[blk] = wsum[0] + wsum[1] + wsum[2] + wsum[3];
}

// ---------------------------------------------------------------------------
// Final deterministic loss reduction: 512 partials -> scalar
// ---------------------------------------------------------------------------
__global__ __launch_bounds__(256) void vq_loss(const float* __restrict__ partials,
                                               float* __restrict__ lossOut) {
  const int tid = threadIdx.x;
  float v = partials[tid] + partials[tid + 256];
  #pragma unroll
  for (int m = 1; m < 64; m <<= 1) v += __shfl_xor(v, m);
  __shared__ float ws2[4];
  if ((tid & 63) == 0) ws2[tid >> 6] = v;
  __syncthreads();
  if (tid == 0)
    lossOut[0] = (ws2[0] + ws2[1] + ws2[2] + ws2[3]) * (1.25f / 16777216.f);
}

extern "C" void kernel_launch(void* const* d_in, const int* in_sizes, int n_in,
                              void* d_out, int out_size, void* d_ws, size_t ws_size,
                              hipStream_t stream) {
  const float* z   = (const float*)d_in[0];   // 65536 x 256 fp32
  const float* emb = (const float*)d_in[1];   // 1024 x 256 fp32
  float* out = (float*)d_out;                 // 16777216 + 1 fp32

  char* ws = (char*)d_ws;
  ushort_t* embT   = (ushort_t*)ws;                  // 512 KB
  float*    enorm  = (float*)(ws + 524288);          // 4 KB
  float*    parts  = (float*)(ws + 524288 + 4096);   // 2 KB

  vq_prep<<<N_E, 256, 0, stream>>>(emb, embT, enorm);
  vq_main<<<N_TOKS / 128, 256, 0, stream>>>(z, emb, embT, enorm, out, parts);
  vq_loss<<<1, 256, 0, stream>>>(parts, out + (size_t)N_TOKS * E_DIM);
}